// Round 12
// baseline (127.817 us; speedup 1.0000x reference)
//
#include <hip/hip_runtime.h>

// SpatialMTP1Hop (R12): DIAGNOSTIC ROUND. Five variants (R5,R7,R9,R10,R11)
// pinned at 39.7-43.6us with three different err bodies and two bucketize
// bodies -> the per-phase cost attribution is unknown (harness 268MB poison
// fills at ~39us flood rocprof top-5; every kernel <38us is invisible).
// This round: separate dispatches, each phase body repeated IN-KERNEL
// (err x3, bucketize x3, reduce x5; all idempotent -- reduce now overwrites
// partial[bk] and a final kernel does the deterministic sum). Repeated
// kernels exceed the fill threshold -> top-5 rows WITH full PMC per phase.
// Same math, absmax 0; total intentionally ~2.5x (one-round cost for data).

#define CNT_SHIFT 44
#define ERR_SCALE 67108864.0f     // 2^26 fixed-point for err
#define BKT_SHIFT 8
#define BKT_SIZE  256
#define P2B       256             // bucketize blocks
#define STASH     6272            // u32 per block region (>= chunk edges 6252)
#define PREF_STRIDE 200           // u16 slots per source block (NB+1 <= 200)
#define REP_ERR   3
#define REP_BKT   3
#define REP_RED   5

__device__ __forceinline__ int owner_fn(int s, bool fast, int C,
                                        const int* __restrict__ arr_idx,
                                        const int* __restrict__ centers) {
    if (fast) return (s < C) ? s : -1;
    int i = arr_idx[s];
    return ((unsigned)i < (unsigned)C && centers[i] == s) ? i : -1;
}

// D1: center scatter + per-block arange validation.
__global__ __launch_bounds__(256)
void prep_kernel(const int* __restrict__ centers,
                 int* __restrict__ arr_idx,
                 int* __restrict__ flagpart,
                 float* __restrict__ out,
                 int C, int out_size) {
    __shared__ int ok;
    int t = threadIdx.x;
    int gtid = blockIdx.x * 256 + t;
    if (t == 0) ok = 1;
    __syncthreads();
    bool mism = false;
    if (gtid < C) {
        int c = centers[gtid];
        arr_idx[c] = gtid;
        mism = (c != gtid);
    }
    if (__ballot(mism) != 0ull && (t & 63) == 0) atomicAnd(&ok, 0);
    __syncthreads();
    if (t == 0) flagpart[blockIdx.x] = ok;
    if (gtid >= 1 && gtid < out_size) out[gtid] = 0.f;   // out[0] set by final
}

// D2: err_node (R5/R10 proven shape: 32 lanes/node, 2 nodes/wave), x REP_ERR.
__global__ __launch_bounds__(256)
void err_kernel(const float* __restrict__ H, const float* __restrict__ W,
                const float* __restrict__ b, const float* __restrict__ target,
                float* __restrict__ err_node, int N) {
    const int t = threadIdx.x;
    const int lane = t & 63, sub = lane >> 5, l32 = lane & 31;
    float wr[12];
    {
        const float* wb = W + (size_t)(4 * l32) * 3;
        #pragma unroll
        for (int r = 0; r < 12; ++r) wr[r] = wb[r];
    }
    const float b0 = b[0], b1 = b[1], b2 = b[2];
    const float4* H4 = reinterpret_cast<const float4*>(H);
    const int wv    = blockIdx.x * 4 + (t >> 6);
    const int EW    = gridDim.x * 4;
    const int npair = (N + 1) >> 1;
    for (int rep = 0; rep < REP_ERR; ++rep) {
        for (int p = wv; p < npair; p += EW) {
            const int node = 2 * p + sub;
            float4 hv = (node < N) ? H4[(size_t)node * 32 + l32]
                                   : make_float4(0.f, 0.f, 0.f, 0.f);
            float hx[4] = {hv.x, hv.y, hv.z, hv.w};
            float a0 = 0.f, a1 = 0.f, a2 = 0.f;
            #pragma unroll
            for (int r = 0; r < 4; ++r) {
                a0 += hx[r] * wr[r * 3 + 0];
                a1 += hx[r] * wr[r * 3 + 1];
                a2 += hx[r] * wr[r * 3 + 2];
            }
            #pragma unroll
            for (int m = 16; m > 0; m >>= 1) {
                a0 += __shfl_xor(a0, m, 64);
                a1 += __shfl_xor(a1, m, 64);
                a2 += __shfl_xor(a2, m, 64);
            }
            if (l32 == 0 && node < N) {
                float e0 = a0 + b0 - target[(size_t)node * 3 + 0];
                float e1 = a1 + b1 - target[(size_t)node * 3 + 1];
                float e2 = a2 + b2 - target[(size_t)node * 3 + 2];
                err_node[node] = (e0*e0 + e1*e1 + e2*e2) * (1.0f / 3.0f);
            }
        }
        __syncthreads();
        asm volatile("" ::: "memory");   // keep reps (no cross-rep elimination)
    }
}

// D3: bucketize (R10 counting sort), x REP_BKT (full re-init per rep).
__global__ __launch_bounds__(256)
void bucketize_kernel(const int* __restrict__ eidx,
                      const int* __restrict__ centers,
                      const int* __restrict__ arr_idx,
                      const int* __restrict__ flagpart,
                      unsigned short* __restrict__ pref_g,
                      unsigned int* __restrict__ pairs,
                      int E, int C, int NB, int NBV) {
    __shared__ unsigned int stash[STASH];
    __shared__ unsigned int hist[256];
    __shared__ unsigned int scan[256];
    __shared__ int okf;
    const int t = threadIdx.x;
    const int E4     = E >> 2;
    const int chunk4 = (E4 + P2B - 1) / P2B;
    const int c0     = blockIdx.x * chunk4;
    const int c1     = min(E4, c0 + chunk4);
    const int4* r0 = reinterpret_cast<const int4*>(eidx);
    const int4* r1 = reinterpret_cast<const int4*>(eidx + E);

    for (int rep = 0; rep < REP_BKT; ++rep) {
        if (t == 0) okf = 1;
        hist[t] = 0u;
        __syncthreads();
        bool my_ok = (t < NBV) ? (flagpart[t] != 0) : true;
        if (__ballot(!my_ok) != 0ull && (t & 63) == 0) atomicAnd(&okf, 0);
        __syncthreads();
        const bool fast = (okf != 0);

        for (int i = c0 + t; i < c1; i += 256) {
            int4 s4 = r0[i];
            int ss[4] = {s4.x, s4.y, s4.z, s4.w};
            #pragma unroll
            for (int k = 0; k < 4; ++k) {
                int o = owner_fn(ss[k], fast, C, arr_idx, centers);
                if (o >= 0) atomicAdd(&hist[(unsigned)o >> BKT_SHIFT], 1u);
            }
        }
        __syncthreads();
        scan[t] = hist[t];
        __syncthreads();
        for (int off = 1; off < 256; off <<= 1) {
            unsigned v = (t >= off) ? scan[t - off] : 0u;
            __syncthreads();
            if (t >= off) scan[t] += v;
            __syncthreads();
        }
        {
            unsigned pre = (t == 0) ? 0u : scan[t - 1];
            hist[t] = pre;
            if (t <= NB)
                pref_g[(size_t)blockIdx.x * PREF_STRIDE + t] = (unsigned short)pre;
        }
        __syncthreads();
        for (int i = c0 + t; i < c1; i += 256) {
            int4 s4 = r0[i];
            int4 d4 = r1[i];
            int ss[4] = {s4.x, s4.y, s4.z, s4.w};
            int dd[4] = {d4.x, d4.y, d4.z, d4.w};
            #pragma unroll
            for (int k = 0; k < 4; ++k) {
                int o = owner_fn(ss[k], fast, C, arr_idx, centers);
                if (o >= 0) {
                    unsigned bk = (unsigned)o >> BKT_SHIFT;
                    unsigned pos = atomicAdd(&hist[bk], 1u);
                    stash[pos] = (((unsigned)o & (BKT_SIZE - 1)) << 17)
                               | (unsigned)dd[k];
                }
            }
        }
        __syncthreads();
        uint4*       dg = reinterpret_cast<uint4*>(pairs + (size_t)blockIdx.x * STASH);
        const uint4* sg = reinterpret_cast<const uint4*>(stash);
        for (int i = t; i < STASH / 4; i += 256) dg[i] = sg[i];
        __syncthreads();
        asm volatile("" ::: "memory");
    }
}

// D4: per-bucket reduce (R10 per-segment form), x REP_RED; OVERWRITES partial[bk].
__global__ __launch_bounds__(256)
void reduce_kernel(const unsigned int* __restrict__ pairs,
                   const unsigned short* __restrict__ pref_g,
                   const float* __restrict__ err_node,
                   float* __restrict__ partial, int C) {
    __shared__ unsigned long long bins[BKT_SIZE];
    __shared__ float wsum[4];
    const int bk = blockIdx.x, t = threadIdx.x;
    for (int rep = 0; rep < REP_RED; ++rep) {
        bins[t] = 0ull;
        __syncthreads();
        {
            const size_t pb = (size_t)t * PREF_STRIDE;
            unsigned start = pref_g[pb + bk];
            unsigned end   = pref_g[pb + bk + 1];
            const unsigned int* reg = pairs + (size_t)t * STASH;
            for (unsigned i = start; i < end; ++i) {
                unsigned p = reg[i];
                float err = err_node[p & 0x1FFFFu];
                atomicAdd(&bins[p >> 17],
                          (1ull << CNT_SHIFT) + (unsigned long long)(err * ERR_SCALE));
            }
        }
        __syncthreads();
        float term = 0.f;
        {
            int center = bk * BKT_SIZE + t;
            if (center < C) {
                unsigned long long u = bins[t];
                float cnt = (float)(u >> CNT_SHIFT);
                float es  = (float)(u & ((1ull << CNT_SHIFT) - 1)) * (1.0f / ERR_SCALE);
                term = es / fmaxf(cnt, 1.0f);
            }
        }
        #pragma unroll
        for (int m = 32; m > 0; m >>= 1) term += __shfl_down(term, m, 64);
        if ((t & 63) == 0) wsum[t >> 6] = term;
        __syncthreads();
        if (t == 0)
            partial[bk] = wsum[0] + wsum[1] + wsum[2] + wsum[3];   // overwrite
        __syncthreads();
        asm volatile("" ::: "memory");
    }
}

// D5: deterministic final sum (single block, fixed order).
__global__ __launch_bounds__(256)
void final_kernel(const float* __restrict__ partial,
                  float* __restrict__ out, int NB, float invC) {
    __shared__ float wsum[4];
    const int t = threadIdx.x;
    float v = (t < NB) ? partial[t] : 0.f;
    #pragma unroll
    for (int m = 32; m > 0; m >>= 1) v += __shfl_down(v, m, 64);
    if ((t & 63) == 0) wsum[t >> 6] = v;
    __syncthreads();
    if (t == 0) out[0] = (wsum[0] + wsum[1] + wsum[2] + wsum[3]) * invC;
}

// ================= fallback (general shapes / small ws) =================
__global__ __launch_bounds__(256)
void fb_err_kernel(const float* __restrict__ H, const float* __restrict__ W,
                   const float* __restrict__ b, const float* __restrict__ target,
                   const int* __restrict__ centers,
                   float* __restrict__ err_node, int* __restrict__ arr_idx,
                   float* __restrict__ out, int N, int C, int D, int DO,
                   int out_size) {
    int gtid = blockIdx.x * blockDim.x + threadIdx.x;
    if (gtid < C) arr_idx[centers[gtid]] = gtid;
    if (gtid < out_size) out[gtid] = 0.f;
    if (gtid < N) {
        float acc = 0.f;
        for (int j = 0; j < DO; ++j) {
            float a = b[j];
            for (int r = 0; r < D; ++r)
                a += H[(size_t)gtid * D + r] * W[(size_t)r * DO + j];
            float e = a - target[(size_t)gtid * DO + j];
            acc += e * e;
        }
        err_node[gtid] = acc / (float)DO;
    }
}

__global__ void fb_edge_kernel(const int* __restrict__ eidx,
                               const int* __restrict__ arr_idx,
                               const int* __restrict__ centers,
                               const float* __restrict__ err_node,
                               unsigned long long* __restrict__ binsg,
                               int E, int C) {
    int e = blockIdx.x * blockDim.x + threadIdx.x;
    if (e >= E) return;
    int s = eidx[e];
    int o = owner_fn(s, false, C, arr_idx, centers);
    if (o >= 0) {
        int d = eidx[E + e];
        unsigned long long add = (1ull << CNT_SHIFT)
                               + (unsigned long long)(err_node[d] * ERR_SCALE);
        atomicAdd(&binsg[o], add);
    }
}

__global__ void fb_finalize_kernel(const unsigned long long* __restrict__ binsg,
                                   float* __restrict__ out, int C) {
    int i = blockIdx.x * blockDim.x + threadIdx.x;
    float term = 0.f;
    if (i < C) {
        unsigned long long u = binsg[i];
        float cnt = (float)(u >> CNT_SHIFT);
        float es  = (float)(u & ((1ull << CNT_SHIFT) - 1)) * (1.0f / ERR_SCALE);
        term = es / fmaxf(cnt, 1.0f);
    }
    #pragma unroll
    for (int m = 32; m > 0; m >>= 1) term += __shfl_down(term, m, 64);
    __shared__ float wsum[4];
    if ((threadIdx.x & 63) == 0) wsum[threadIdx.x >> 6] = term;
    __syncthreads();
    if (threadIdx.x == 0)
        atomicAdd(out, (wsum[0] + wsum[1] + wsum[2] + wsum[3]) / (float)C);
}

extern "C" void kernel_launch(void* const* d_in, const int* in_sizes, int n_in,
                              void* d_out, int out_size, void* d_ws, size_t ws_size,
                              hipStream_t stream) {
    const float* H      = (const float*)d_in[0];
    const float* W      = (const float*)d_in[1];
    const float* b      = (const float*)d_in[2];
    const float* target = (const float*)d_in[3];
    const int*   eidx   = (const int*)d_in[4];
    const int*   ctrs   = (const int*)d_in[5];

    const int DO = in_sizes[2];
    const int D  = in_sizes[1] / DO;     // 128
    const int N  = in_sizes[0] / D;      // 100000
    const int E  = in_sizes[4] / 2;      // 1600000
    const int C  = in_sizes[5];          // 50000
    const int NB  = (C + BKT_SIZE - 1) >> BKT_SHIFT;  // 196
    const int NBV = (C + 255) / 256;                  // 196

    size_t off = 0;
    auto take = [&](size_t bytes) {
        void* p = (char*)d_ws + off;
        off = (off + bytes + 255) & ~255ull;
        return p;
    };
    float*          err_node = (float*)take((size_t)N * 4);
    int*            arr_idx  = (int*)take((size_t)N * 4);
    int*            flagpart = (int*)take((size_t)NBV * 4);
    unsigned short* pref_g   = (unsigned short*)take((size_t)P2B * PREF_STRIDE * 2);
    float*          partial  = (float*)take((size_t)NB * 4);
    unsigned int*   pairs    = (unsigned int*)((char*)d_ws + off);
    size_t need = off + (size_t)P2B * STASH * 4;

    int chunk_edges = 4 * ((E / 4 + P2B - 1) / P2B);
    bool fits = (ws_size >= need) && (NB + 1 <= PREF_STRIDE) && (NBV <= 256) &&
                (N < (1 << 17)) && ((E & 3) == 0) && (chunk_edges <= STASH) &&
                (D == 128) && (DO == 3) && (out_size >= 1);
    if (fits) {
        prep_kernel<<<NBV, 256, 0, stream>>>(ctrs, arr_idx, flagpart,
                                             (float*)d_out, C, out_size);
        err_kernel<<<1024, 256, 0, stream>>>(H, W, b, target, err_node, N);
        bucketize_kernel<<<P2B, 256, 0, stream>>>(eidx, ctrs, arr_idx, flagpart,
                                                  pref_g, pairs, E, C, NB, NBV);
        reduce_kernel<<<NB, 256, 0, stream>>>(pairs, pref_g, err_node,
                                              partial, C);
        final_kernel<<<1, 256, 0, stream>>>(partial, (float*)d_out, NB,
                                            1.0f / (float)C);
    } else {
        unsigned long long* binsg = (unsigned long long*)((char*)d_ws + off);
        hipMemsetAsync(binsg, 0, (size_t)C * 8, stream);
        int thr = 256;
        fb_err_kernel<<<(max(N, C) + thr - 1) / thr, thr, 0, stream>>>(
            H, W, b, target, ctrs, err_node, arr_idx, (float*)d_out,
            N, C, D, DO, out_size);
        fb_edge_kernel<<<(E + thr - 1) / thr, thr, 0, stream>>>(
            eidx, arr_idx, ctrs, err_node, binsg, E, C);
        fb_finalize_kernel<<<(C + thr - 1) / thr, thr, 0, stream>>>(
            binsg, (float*)d_out, C);
    }
}

// Round 13
// 35.164 us; speedup vs baseline: 3.6348x; 3.6348x over previous
//
#include <hip/hip_runtime.h>

// SpatialMTP1Hop (R13). R12 diagnostic attribution (direct PMC):
//   reduce = 10.8us at 7.3% occupancy (196 blocks x 4 waves, 1/CU) -- pure
//   latency starvation; err+bkt = 22.5us combined; prep~1; overhead~4.
// R13: reduce at 1024 thr/block (4 thr/segment: quad reads 16 contiguous
// bytes, 4x TLP, serial depth 16->4); bucketize streams only `total` used
// entries (was full 25KB region). Everything else keeps the proven shape.
// Exact u64 fixed-point accumulation -> deterministic, absmax 0.

#define CNT_SHIFT 44
#define ERR_SCALE 67108864.0f     // 2^26 fixed-point for err
#define BKT_SHIFT 8
#define BKT_SIZE  256
#define P2B       256             // bucketize blocks
#define ERRB      512             // err blocks in mid
#define BTHR      512
#define STASH     6272            // u32 per block region (>= max chunk 6252)
#define PREF_STRIDE 200           // u16 slots per source block (NB+1 <= 200)

__device__ __forceinline__ int owner_fn(int s, bool fast, int C,
                                        const int* __restrict__ arr_idx,
                                        const int* __restrict__ centers) {
    if (fast) return (s < C) ? s : -1;
    int i = arr_idx[s];
    return ((unsigned)i < (unsigned)C && centers[i] == s) ? i : -1;
}

// D1: center scatter + per-block arange validation + out tail zeroing.
__global__ __launch_bounds__(256)
void prep_kernel(const int* __restrict__ centers,
                 int* __restrict__ arr_idx,
                 int* __restrict__ flagpart,
                 float* __restrict__ out,
                 int C, int out_size) {
    __shared__ int ok;
    int t = threadIdx.x;
    int gtid = blockIdx.x * 256 + t;
    if (t == 0) ok = 1;
    __syncthreads();
    bool mism = false;
    if (gtid < C) {
        int c = centers[gtid];
        arr_idx[c] = gtid;                 // scatter-only, no sentinel needed
        mism = (c != gtid);
    }
    if (__ballot(mism) != 0ull && (t & 63) == 0) atomicAnd(&ok, 0);
    __syncthreads();
    if (t == 0) flagpart[blockIdx.x] = ok;
    if (gtid >= 1 && gtid < out_size) out[gtid] = 0.f;   // out[0] by final
}

// D2: blocks [0,P2B): counting-sort bucketize; [P2B,P2B+ERRB): err_node.
__global__ __launch_bounds__(BTHR)
void mid_kernel(const float* __restrict__ H, const float* __restrict__ W,
                const float* __restrict__ b, const float* __restrict__ target,
                const int* __restrict__ eidx, const int* __restrict__ centers,
                const int* __restrict__ arr_idx,
                const int* __restrict__ flagpart,
                float* __restrict__ err_node,
                unsigned short* __restrict__ pref_g,
                unsigned int* __restrict__ pairs,
                int N, int E, int C, int NB, int NBV) {
    __shared__ unsigned int stash[STASH];
    __shared__ unsigned int hist[256];
    __shared__ unsigned int scan[256];
    __shared__ unsigned int total_sh;
    __shared__ int okf;
    const int t = threadIdx.x;

    if (blockIdx.x < P2B) {
        // ------------- bucketize (block-local counting sort, 512 thr) -------------
        if (t == 0) okf = 1;
        if (t < 256) hist[t] = 0u;
        __syncthreads();
        bool my_ok = (t < NBV) ? (flagpart[t] != 0) : true;
        if (__ballot(!my_ok) != 0ull && (t & 63) == 0) atomicAnd(&okf, 0);
        __syncthreads();
        const bool fast = (okf != 0);

        const int E4     = E >> 2;                    // (E&3)==0 host-gated
        const int chunk4 = (E4 + P2B - 1) / P2B;
        const int c0     = blockIdx.x * chunk4;
        const int c1     = min(E4, c0 + chunk4);
        const int4* r0 = reinterpret_cast<const int4*>(eidx);
        const int4* r1 = reinterpret_cast<const int4*>(eidx + E);

        // pass 1: histogram
        for (int i = c0 + t; i < c1; i += BTHR) {
            int4 s4 = r0[i];
            int ss[4] = {s4.x, s4.y, s4.z, s4.w};
            #pragma unroll
            for (int k = 0; k < 4; ++k) {
                int o = owner_fn(ss[k], fast, C, arr_idx, centers);
                if (o >= 0) atomicAdd(&hist[(unsigned)o >> BKT_SHIFT], 1u);
            }
        }
        __syncthreads();
        if (t < 256) scan[t] = hist[t];
        __syncthreads();
        for (int off = 1; off < 256; off <<= 1) {
            unsigned v = (t < 256 && t >= off) ? scan[t - off] : 0u;
            __syncthreads();
            if (t < 256 && t >= off) scan[t] += v;
            __syncthreads();
        }
        if (t < 256) {
            unsigned pre = (t == 0) ? 0u : scan[t - 1];
            hist[t] = pre;                               // cursor
            if (t <= NB)
                pref_g[(size_t)blockIdx.x * PREF_STRIDE + t] = (unsigned short)pre;
        }
        if (t == 0) total_sh = scan[255];
        __syncthreads();
        // pass 2: LDS scatter
        for (int i = c0 + t; i < c1; i += BTHR) {
            int4 s4 = r0[i];
            int4 d4 = r1[i];
            int ss[4] = {s4.x, s4.y, s4.z, s4.w};
            int dd[4] = {d4.x, d4.y, d4.z, d4.w};
            #pragma unroll
            for (int k = 0; k < 4; ++k) {
                int o = owner_fn(ss[k], fast, C, arr_idx, centers);
                if (o >= 0) {
                    unsigned bk = (unsigned)o >> BKT_SHIFT;
                    unsigned pos = atomicAdd(&hist[bk], 1u);
                    stash[pos] = (((unsigned)o & (BKT_SIZE - 1)) << 17)
                               | (unsigned)dd[k];
                }
            }
        }
        __syncthreads();
        // stream out only the used entries (coalesced uint4)
        {
            unsigned nvec = (total_sh + 3u) >> 2;
            uint4*       dg = reinterpret_cast<uint4*>(pairs + (size_t)blockIdx.x * STASH);
            const uint4* sg = reinterpret_cast<const uint4*>(stash);
            for (unsigned i = t; i < nvec; i += BTHR) dg[i] = sg[i];
        }
    } else {
        // ------------- err_node (proven R5 shape, 512 thr, grid-stride) -------------
        const int lane = t & 63, sub = lane >> 5, l32 = lane & 31;
        float wr[12];
        {
            const float* wb = W + (size_t)(4 * l32) * 3;
            #pragma unroll
            for (int r = 0; r < 12; ++r) wr[r] = wb[r];
        }
        const float b0 = b[0], b1 = b[1], b2 = b[2];
        const float4* H4 = reinterpret_cast<const float4*>(H);
        const int wv    = (blockIdx.x - P2B) * (BTHR >> 6) + (t >> 6);
        const int EW    = ERRB * (BTHR >> 6);
        const int npair = (N + 1) >> 1;
        for (int p = wv; p < npair; p += EW) {
            const int node = 2 * p + sub;
            float4 hv = (node < N) ? H4[(size_t)node * 32 + l32]
                                   : make_float4(0.f, 0.f, 0.f, 0.f);
            float hx[4] = {hv.x, hv.y, hv.z, hv.w};
            float a0 = 0.f, a1 = 0.f, a2 = 0.f;
            #pragma unroll
            for (int r = 0; r < 4; ++r) {
                a0 += hx[r] * wr[r * 3 + 0];
                a1 += hx[r] * wr[r * 3 + 1];
                a2 += hx[r] * wr[r * 3 + 2];
            }
            #pragma unroll
            for (int m = 16; m > 0; m >>= 1) {
                a0 += __shfl_xor(a0, m, 64);
                a1 += __shfl_xor(a1, m, 64);
                a2 += __shfl_xor(a2, m, 64);
            }
            if (l32 == 0 && node < N) {
                float e0 = a0 + b0 - target[(size_t)node * 3 + 0];
                float e1 = a1 + b1 - target[(size_t)node * 3 + 1];
                float e2 = a2 + b2 - target[(size_t)node * 3 + 2];
                err_node[node] = (e0*e0 + e1*e1 + e2*e2) * (1.0f / 3.0f);
            }
        }
    }
}

// D3: per-bucket reduce, 1024 threads, 4 threads per source segment.
__global__ __launch_bounds__(1024)
void reduce_kernel(const unsigned int* __restrict__ pairs,
                   const unsigned short* __restrict__ pref_g,
                   const float* __restrict__ err_node,
                   float* __restrict__ partial, int C) {
    __shared__ unsigned long long bins[BKT_SIZE];
    __shared__ float wsum[16];
    const int bk = blockIdx.x, t = threadIdx.x;
    if (t < BKT_SIZE) bins[t] = 0ull;
    __syncthreads();
    {
        const int seg = t >> 2;            // source block 0..255
        const int j   = t & 3;
        const size_t pb = (size_t)seg * PREF_STRIDE;
        unsigned start = pref_g[pb + bk];
        unsigned end   = pref_g[pb + bk + 1];
        const unsigned int* reg = pairs + (size_t)seg * STASH;
        for (unsigned i = start + j; i < end; i += 4) {
            unsigned p = reg[i];
            float err = err_node[p & 0x1FFFFu];
            atomicAdd(&bins[p >> 17],
                      (1ull << CNT_SHIFT) + (unsigned long long)(err * ERR_SCALE));
        }
    }
    __syncthreads();
    float term = 0.f;
    if (t < BKT_SIZE) {
        int center = bk * BKT_SIZE + t;
        if (center < C) {
            unsigned long long u = bins[t];
            float cnt = (float)(u >> CNT_SHIFT);
            float es  = (float)(u & ((1ull << CNT_SHIFT) - 1)) * (1.0f / ERR_SCALE);
            term = es / fmaxf(cnt, 1.0f);
        }
    }
    #pragma unroll
    for (int m = 32; m > 0; m >>= 1) term += __shfl_down(term, m, 64);
    if ((t & 63) == 0) wsum[t >> 6] = term;
    __syncthreads();
    if (t == 0) {
        float s = 0.f;
        #pragma unroll
        for (int w = 0; w < 16; ++w) s += wsum[w];
        partial[bk] = s;                    // overwrite: idempotent
    }
}

// D4: deterministic final sum (single block, fixed order).
__global__ __launch_bounds__(256)
void final_kernel(const float* __restrict__ partial,
                  float* __restrict__ out, int NB, float invC) {
    __shared__ float wsum[4];
    const int t = threadIdx.x;
    float v = (t < NB) ? partial[t] : 0.f;
    #pragma unroll
    for (int m = 32; m > 0; m >>= 1) v += __shfl_down(v, m, 64);
    if ((t & 63) == 0) wsum[t >> 6] = v;
    __syncthreads();
    if (t == 0) out[0] = (wsum[0] + wsum[1] + wsum[2] + wsum[3]) * invC;
}

// ================= fallback (general shapes / small ws) =================
__global__ __launch_bounds__(256)
void fb_err_kernel(const float* __restrict__ H, const float* __restrict__ W,
                   const float* __restrict__ b, const float* __restrict__ target,
                   const int* __restrict__ centers,
                   float* __restrict__ err_node, int* __restrict__ arr_idx,
                   float* __restrict__ out, int N, int C, int D, int DO,
                   int out_size) {
    int gtid = blockIdx.x * blockDim.x + threadIdx.x;
    if (gtid < C) arr_idx[centers[gtid]] = gtid;
    if (gtid < out_size) out[gtid] = 0.f;
    if (gtid < N) {
        float acc = 0.f;
        for (int j = 0; j < DO; ++j) {
            float a = b[j];
            for (int r = 0; r < D; ++r)
                a += H[(size_t)gtid * D + r] * W[(size_t)r * DO + j];
            float e = a - target[(size_t)gtid * DO + j];
            acc += e * e;
        }
        err_node[gtid] = acc / (float)DO;
    }
}

__global__ void fb_edge_kernel(const int* __restrict__ eidx,
                               const int* __restrict__ arr_idx,
                               const int* __restrict__ centers,
                               const float* __restrict__ err_node,
                               unsigned long long* __restrict__ binsg,
                               int E, int C) {
    int e = blockIdx.x * blockDim.x + threadIdx.x;
    if (e >= E) return;
    int s = eidx[e];
    int o = owner_fn(s, false, C, arr_idx, centers);
    if (o >= 0) {
        int d = eidx[E + e];
        unsigned long long add = (1ull << CNT_SHIFT)
                               + (unsigned long long)(err_node[d] * ERR_SCALE);
        atomicAdd(&binsg[o], add);
    }
}

__global__ void fb_finalize_kernel(const unsigned long long* __restrict__ binsg,
                                   float* __restrict__ out, int C) {
    int i = blockIdx.x * blockDim.x + threadIdx.x;
    float term = 0.f;
    if (i < C) {
        unsigned long long u = binsg[i];
        float cnt = (float)(u >> CNT_SHIFT);
        float es  = (float)(u & ((1ull << CNT_SHIFT) - 1)) * (1.0f / ERR_SCALE);
        term = es / fmaxf(cnt, 1.0f);
    }
    #pragma unroll
    for (int m = 32; m > 0; m >>= 1) term += __shfl_down(term, m, 64);
    __shared__ float wsum[4];
    if ((threadIdx.x & 63) == 0) wsum[threadIdx.x >> 6] = term;
    __syncthreads();
    if (threadIdx.x == 0)
        atomicAdd(out, (wsum[0] + wsum[1] + wsum[2] + wsum[3]) / (float)C);
}

extern "C" void kernel_launch(void* const* d_in, const int* in_sizes, int n_in,
                              void* d_out, int out_size, void* d_ws, size_t ws_size,
                              hipStream_t stream) {
    const float* H      = (const float*)d_in[0];
    const float* W      = (const float*)d_in[1];
    const float* b      = (const float*)d_in[2];
    const float* target = (const float*)d_in[3];
    const int*   eidx   = (const int*)d_in[4];
    const int*   ctrs   = (const int*)d_in[5];

    const int DO = in_sizes[2];
    const int D  = in_sizes[1] / DO;     // 128
    const int N  = in_sizes[0] / D;      // 100000
    const int E  = in_sizes[4] / 2;      // 1600000
    const int C  = in_sizes[5];          // 50000
    const int NB  = (C + BKT_SIZE - 1) >> BKT_SHIFT;  // 196
    const int NBV = (C + 255) / 256;                  // 196

    size_t off = 0;
    auto take = [&](size_t bytes) {
        void* p = (char*)d_ws + off;
        off = (off + bytes + 255) & ~255ull;
        return p;
    };
    float*          err_node = (float*)take((size_t)N * 4);
    int*            arr_idx  = (int*)take((size_t)N * 4);
    int*            flagpart = (int*)take((size_t)NBV * 4);
    unsigned short* pref_g   = (unsigned short*)take((size_t)P2B * PREF_STRIDE * 2);
    float*          partial  = (float*)take((size_t)NB * 4);
    unsigned int*   pairs    = (unsigned int*)((char*)d_ws + off);
    size_t need = off + (size_t)P2B * STASH * 4;

    int chunk_edges = 4 * ((E / 4 + P2B - 1) / P2B);
    bool fits = (ws_size >= need) && (NB + 1 <= PREF_STRIDE) && (NBV <= BTHR) &&
                (N < (1 << 17)) && ((E & 3) == 0) && (chunk_edges <= STASH) &&
                (D == 128) && (DO == 3) && (out_size >= 1);
    if (fits) {
        prep_kernel<<<NBV, 256, 0, stream>>>(ctrs, arr_idx, flagpart,
                                             (float*)d_out, C, out_size);
        mid_kernel<<<P2B + ERRB, BTHR, 0, stream>>>(H, W, b, target, eidx,
                                                    ctrs, arr_idx, flagpart,
                                                    err_node, pref_g, pairs,
                                                    N, E, C, NB, NBV);
        reduce_kernel<<<NB, 1024, 0, stream>>>(pairs, pref_g, err_node,
                                               partial, C);
        final_kernel<<<1, 256, 0, stream>>>(partial, (float*)d_out, NB,
                                            1.0f / (float)C);
    } else {
        unsigned long long* binsg = (unsigned long long*)((char*)d_ws + off);
        hipMemsetAsync(binsg, 0, (size_t)C * 8, stream);
        int thr = 256;
        fb_err_kernel<<<(max(N, C) + thr - 1) / thr, thr, 0, stream>>>(
            H, W, b, target, ctrs, err_node, arr_idx, (float*)d_out,
            N, C, D, DO, out_size);
        fb_edge_kernel<<<(E + thr - 1) / thr, thr, 0, stream>>>(
            eidx, arr_idx, ctrs, err_node, binsg, E, C);
        fb_finalize_kernel<<<(C + thr - 1) / thr, thr, 0, stream>>>(
            binsg, (float*)d_out, C);
    }
}

// Round 14
// 34.871 us; speedup vs baseline: 3.6654x; 1.0084x over previous
//
#include <hip/hip_runtime.h>

// SpatialMTP1Hop (R14): occupancy round.
// R13 ledger: prep 1 + mid 24 (err 12.5 + bkt 10, SUM not max) + reduce 4.5
// + final 0.3 + overhead 4 = 35.2. R13's reduce proved these latency-bound
// phases scale with waves (10.8->4.5 at 4x occupancy). R14: err at 32
// waves/CU (2048 blocks, prep fused in -- independent work), bkt at 16
// waves/CU (1024 thr/block). If total doesn't move, phases sit at the L3 BW
// ceiling (~90MB/3.5TB/s ~ 26us) and we're near the structural floor.
// Exact u64 fixed-point accumulation -> deterministic, absmax 0.

#define CNT_SHIFT 44
#define ERR_SCALE 67108864.0f     // 2^26 fixed-point for err
#define BKT_SHIFT 8
#define BKT_SIZE  256
#define P2B       256             // bucketize blocks
#define BKT_THR   1024
#define ERRBLKS   2048            // err blocks (8/CU x 4 waves = 32 waves/CU)
#define STASH     6272            // u32 per block region (>= max chunk 6252)
#define PREF_STRIDE 200           // u16 slots per source block (NB+1 <= 200)

__device__ __forceinline__ int owner_fn(int s, bool fast, int C,
                                        const int* __restrict__ arr_idx,
                                        const int* __restrict__ centers) {
    if (fast) return (s < C) ? s : -1;
    int i = arr_idx[s];
    return ((unsigned)i < (unsigned)C && centers[i] == s) ? i : -1;
}

// D1: prep (blocks < NBV) + err_node (all blocks, grid-stride, 32 waves/CU).
__global__ __launch_bounds__(256)
void prep_err_kernel(const float* __restrict__ H, const float* __restrict__ W,
                     const float* __restrict__ b, const float* __restrict__ target,
                     const int* __restrict__ centers,
                     float* __restrict__ err_node,
                     int* __restrict__ arr_idx,
                     int* __restrict__ flagpart,
                     float* __restrict__ out,
                     int N, int C, int NBV, int out_size) {
    __shared__ int ok;
    const int t = threadIdx.x;
    const int gtid = blockIdx.x * 256 + t;

    // ---- prep role (independent of err role) ----
    if (blockIdx.x < NBV) {
        if (t == 0) ok = 1;
        __syncthreads();
        bool mism = false;
        if (gtid < C) {
            int c = centers[gtid];
            arr_idx[c] = gtid;             // scatter-only, no sentinel needed
            mism = (c != gtid);
        }
        if (__ballot(mism) != 0ull && (t & 63) == 0) atomicAnd(&ok, 0);
        __syncthreads();
        if (t == 0) flagpart[blockIdx.x] = ok;
    }
    if (gtid >= 1 && gtid < out_size) out[gtid] = 0.f;   // out[0] by final

    // ---- err role (proven R5 shape: 32 lanes/node, 2 nodes/wave) ----
    const int lane = t & 63, sub = lane >> 5, l32 = lane & 31;
    float wr[12];
    {
        const float* wb = W + (size_t)(4 * l32) * 3;
        #pragma unroll
        for (int r = 0; r < 12; ++r) wr[r] = wb[r];
    }
    const float b0 = b[0], b1 = b[1], b2 = b[2];
    const float4* H4 = reinterpret_cast<const float4*>(H);
    const int wv    = blockIdx.x * 4 + (t >> 6);
    const int EW    = ERRBLKS * 4;
    const int npair = (N + 1) >> 1;
    for (int p = wv; p < npair; p += EW) {
        const int node = 2 * p + sub;
        float4 hv = (node < N) ? H4[(size_t)node * 32 + l32]
                               : make_float4(0.f, 0.f, 0.f, 0.f);
        float hx[4] = {hv.x, hv.y, hv.z, hv.w};
        float a0 = 0.f, a1 = 0.f, a2 = 0.f;
        #pragma unroll
        for (int r = 0; r < 4; ++r) {
            a0 += hx[r] * wr[r * 3 + 0];
            a1 += hx[r] * wr[r * 3 + 1];
            a2 += hx[r] * wr[r * 3 + 2];
        }
        #pragma unroll
        for (int m = 16; m > 0; m >>= 1) {
            a0 += __shfl_xor(a0, m, 64);
            a1 += __shfl_xor(a1, m, 64);
            a2 += __shfl_xor(a2, m, 64);
        }
        if (l32 == 0 && node < N) {
            float e0 = a0 + b0 - target[(size_t)node * 3 + 0];
            float e1 = a1 + b1 - target[(size_t)node * 3 + 1];
            float e2 = a2 + b2 - target[(size_t)node * 3 + 2];
            err_node[node] = (e0*e0 + e1*e1 + e2*e2) * (1.0f / 3.0f);
        }
    }
}

// D2: bucketize (block-local counting sort), 1024 threads (16 waves/CU).
__global__ __launch_bounds__(BKT_THR)
void bucketize_kernel(const int* __restrict__ eidx,
                      const int* __restrict__ centers,
                      const int* __restrict__ arr_idx,
                      const int* __restrict__ flagpart,
                      unsigned short* __restrict__ pref_g,
                      unsigned int* __restrict__ pairs,
                      int E, int C, int NB, int NBV) {
    __shared__ unsigned int stash[STASH];
    __shared__ unsigned int hist[256];
    __shared__ unsigned int scan[256];
    __shared__ unsigned int total_sh;
    __shared__ int okf;
    const int t = threadIdx.x;

    if (t == 0) okf = 1;
    if (t < 256) hist[t] = 0u;
    __syncthreads();
    bool my_ok = (t < NBV) ? (flagpart[t] != 0) : true;
    if (__ballot(!my_ok) != 0ull && (t & 63) == 0) atomicAnd(&okf, 0);
    __syncthreads();
    const bool fast = (okf != 0);

    const int E4     = E >> 2;                    // (E&3)==0 host-gated
    const int chunk4 = (E4 + P2B - 1) / P2B;
    const int c0     = blockIdx.x * chunk4;
    const int c1     = min(E4, c0 + chunk4);
    const int4* r0 = reinterpret_cast<const int4*>(eidx);
    const int4* r1 = reinterpret_cast<const int4*>(eidx + E);

    // pass 1: histogram
    for (int i = c0 + t; i < c1; i += BKT_THR) {
        int4 s4 = r0[i];
        int ss[4] = {s4.x, s4.y, s4.z, s4.w};
        #pragma unroll
        for (int k = 0; k < 4; ++k) {
            int o = owner_fn(ss[k], fast, C, arr_idx, centers);
            if (o >= 0) atomicAdd(&hist[(unsigned)o >> BKT_SHIFT], 1u);
        }
    }
    __syncthreads();
    if (t < 256) scan[t] = hist[t];
    __syncthreads();
    for (int off = 1; off < 256; off <<= 1) {
        unsigned v = (t < 256 && t >= off) ? scan[t - off] : 0u;
        __syncthreads();
        if (t < 256 && t >= off) scan[t] += v;
        __syncthreads();
    }
    if (t < 256) {
        unsigned pre = (t == 0) ? 0u : scan[t - 1];
        hist[t] = pre;                               // cursor
        if (t <= NB)
            pref_g[(size_t)blockIdx.x * PREF_STRIDE + t] = (unsigned short)pre;
    }
    if (t == 0) total_sh = scan[255];
    __syncthreads();
    // pass 2: LDS scatter
    for (int i = c0 + t; i < c1; i += BKT_THR) {
        int4 s4 = r0[i];
        int4 d4 = r1[i];
        int ss[4] = {s4.x, s4.y, s4.z, s4.w};
        int dd[4] = {d4.x, d4.y, d4.z, d4.w};
        #pragma unroll
        for (int k = 0; k < 4; ++k) {
            int o = owner_fn(ss[k], fast, C, arr_idx, centers);
            if (o >= 0) {
                unsigned bk = (unsigned)o >> BKT_SHIFT;
                unsigned pos = atomicAdd(&hist[bk], 1u);
                stash[pos] = (((unsigned)o & (BKT_SIZE - 1)) << 17)
                           | (unsigned)dd[k];
            }
        }
    }
    __syncthreads();
    // stream out only the used entries (coalesced uint4)
    {
        unsigned nvec = (total_sh + 3u) >> 2;
        uint4*       dg = reinterpret_cast<uint4*>(pairs + (size_t)blockIdx.x * STASH);
        const uint4* sg = reinterpret_cast<const uint4*>(stash);
        for (unsigned i = t; i < nvec; i += BKT_THR) dg[i] = sg[i];
    }
}

// D3: per-bucket reduce, 1024 threads, 4 threads per source segment.
__global__ __launch_bounds__(1024)
void reduce_kernel(const unsigned int* __restrict__ pairs,
                   const unsigned short* __restrict__ pref_g,
                   const float* __restrict__ err_node,
                   float* __restrict__ partial, int C) {
    __shared__ unsigned long long bins[BKT_SIZE];
    __shared__ float wsum[16];
    const int bk = blockIdx.x, t = threadIdx.x;
    if (t < BKT_SIZE) bins[t] = 0ull;
    __syncthreads();
    {
        const int seg = t >> 2;            // source block 0..255
        const int j   = t & 3;
        const size_t pb = (size_t)seg * PREF_STRIDE;
        unsigned start = pref_g[pb + bk];
        unsigned end   = pref_g[pb + bk + 1];
        const unsigned int* reg = pairs + (size_t)seg * STASH;
        for (unsigned i = start + j; i < end; i += 4) {
            unsigned p = reg[i];
            float err = err_node[p & 0x1FFFFu];
            atomicAdd(&bins[p >> 17],
                      (1ull << CNT_SHIFT) + (unsigned long long)(err * ERR_SCALE));
        }
    }
    __syncthreads();
    float term = 0.f;
    if (t < BKT_SIZE) {
        int center = bk * BKT_SIZE + t;
        if (center < C) {
            unsigned long long u = bins[t];
            float cnt = (float)(u >> CNT_SHIFT);
            float es  = (float)(u & ((1ull << CNT_SHIFT) - 1)) * (1.0f / ERR_SCALE);
            term = es / fmaxf(cnt, 1.0f);
        }
    }
    #pragma unroll
    for (int m = 32; m > 0; m >>= 1) term += __shfl_down(term, m, 64);
    if ((t & 63) == 0) wsum[t >> 6] = term;
    __syncthreads();
    if (t == 0) {
        float s = 0.f;
        #pragma unroll
        for (int w = 0; w < 16; ++w) s += wsum[w];
        partial[bk] = s;                    // overwrite: idempotent
    }
}

// D4: deterministic final sum (single block, fixed order).
__global__ __launch_bounds__(256)
void final_kernel(const float* __restrict__ partial,
                  float* __restrict__ out, int NB, float invC) {
    __shared__ float wsum[4];
    const int t = threadIdx.x;
    float v = (t < NB) ? partial[t] : 0.f;
    #pragma unroll
    for (int m = 32; m > 0; m >>= 1) v += __shfl_down(v, m, 64);
    if ((t & 63) == 0) wsum[t >> 6] = v;
    __syncthreads();
    if (t == 0) out[0] = (wsum[0] + wsum[1] + wsum[2] + wsum[3]) * invC;
}

// ================= fallback (general shapes / small ws) =================
__global__ __launch_bounds__(256)
void fb_err_kernel(const float* __restrict__ H, const float* __restrict__ W,
                   const float* __restrict__ b, const float* __restrict__ target,
                   const int* __restrict__ centers,
                   float* __restrict__ err_node, int* __restrict__ arr_idx,
                   float* __restrict__ out, int N, int C, int D, int DO,
                   int out_size) {
    int gtid = blockIdx.x * blockDim.x + threadIdx.x;
    if (gtid < C) arr_idx[centers[gtid]] = gtid;
    if (gtid < out_size) out[gtid] = 0.f;
    if (gtid < N) {
        float acc = 0.f;
        for (int j = 0; j < DO; ++j) {
            float a = b[j];
            for (int r = 0; r < D; ++r)
                a += H[(size_t)gtid * D + r] * W[(size_t)r * DO + j];
            float e = a - target[(size_t)gtid * DO + j];
            acc += e * e;
        }
        err_node[gtid] = acc / (float)DO;
    }
}

__global__ void fb_edge_kernel(const int* __restrict__ eidx,
                               const int* __restrict__ arr_idx,
                               const int* __restrict__ centers,
                               const float* __restrict__ err_node,
                               unsigned long long* __restrict__ binsg,
                               int E, int C) {
    int e = blockIdx.x * blockDim.x + threadIdx.x;
    if (e >= E) return;
    int s = eidx[e];
    int o = owner_fn(s, false, C, arr_idx, centers);
    if (o >= 0) {
        int d = eidx[E + e];
        unsigned long long add = (1ull << CNT_SHIFT)
                               + (unsigned long long)(err_node[d] * ERR_SCALE);
        atomicAdd(&binsg[o], add);
    }
}

__global__ void fb_finalize_kernel(const unsigned long long* __restrict__ binsg,
                                   float* __restrict__ out, int C) {
    int i = blockIdx.x * blockDim.x + threadIdx.x;
    float term = 0.f;
    if (i < C) {
        unsigned long long u = binsg[i];
        float cnt = (float)(u >> CNT_SHIFT);
        float es  = (float)(u & ((1ull << CNT_SHIFT) - 1)) * (1.0f / ERR_SCALE);
        term = es / fmaxf(cnt, 1.0f);
    }
    #pragma unroll
    for (int m = 32; m > 0; m >>= 1) term += __shfl_down(term, m, 64);
    __shared__ float wsum[4];
    if ((threadIdx.x & 63) == 0) wsum[threadIdx.x >> 6] = term;
    __syncthreads();
    if (threadIdx.x == 0)
        atomicAdd(out, (wsum[0] + wsum[1] + wsum[2] + wsum[3]) / (float)C);
}

extern "C" void kernel_launch(void* const* d_in, const int* in_sizes, int n_in,
                              void* d_out, int out_size, void* d_ws, size_t ws_size,
                              hipStream_t stream) {
    const float* H      = (const float*)d_in[0];
    const float* W      = (const float*)d_in[1];
    const float* b      = (const float*)d_in[2];
    const float* target = (const float*)d_in[3];
    const int*   eidx   = (const int*)d_in[4];
    const int*   ctrs   = (const int*)d_in[5];

    const int DO = in_sizes[2];
    const int D  = in_sizes[1] / DO;     // 128
    const int N  = in_sizes[0] / D;      // 100000
    const int E  = in_sizes[4] / 2;      // 1600000
    const int C  = in_sizes[5];          // 50000
    const int NB  = (C + BKT_SIZE - 1) >> BKT_SHIFT;  // 196
    const int NBV = (C + 255) / 256;                  // 196

    size_t off = 0;
    auto take = [&](size_t bytes) {
        void* p = (char*)d_ws + off;
        off = (off + bytes + 255) & ~255ull;
        return p;
    };
    float*          err_node = (float*)take((size_t)N * 4);
    int*            arr_idx  = (int*)take((size_t)N * 4);
    int*            flagpart = (int*)take((size_t)NBV * 4);
    unsigned short* pref_g   = (unsigned short*)take((size_t)P2B * PREF_STRIDE * 2);
    float*          partial  = (float*)take((size_t)NB * 4);
    unsigned int*   pairs    = (unsigned int*)((char*)d_ws + off);
    size_t need = off + (size_t)P2B * STASH * 4;

    int chunk_edges = 4 * ((E / 4 + P2B - 1) / P2B);
    bool fits = (ws_size >= need) && (NB + 1 <= PREF_STRIDE) && (NBV <= BKT_THR) &&
                (NBV <= ERRBLKS) && (N < (1 << 17)) && ((E & 3) == 0) &&
                (chunk_edges <= STASH) && (D == 128) && (DO == 3) && (out_size >= 1);
    if (fits) {
        prep_err_kernel<<<ERRBLKS, 256, 0, stream>>>(H, W, b, target, ctrs,
                                                     err_node, arr_idx, flagpart,
                                                     (float*)d_out, N, C, NBV,
                                                     out_size);
        bucketize_kernel<<<P2B, BKT_THR, 0, stream>>>(eidx, ctrs, arr_idx,
                                                      flagpart, pref_g, pairs,
                                                      E, C, NB, NBV);
        reduce_kernel<<<NB, 1024, 0, stream>>>(pairs, pref_g, err_node,
                                               partial, C);
        final_kernel<<<1, 256, 0, stream>>>(partial, (float*)d_out, NB,
                                            1.0f / (float)C);
    } else {
        unsigned long long* binsg = (unsigned long long*)((char*)d_ws + off);
        hipMemsetAsync(binsg, 0, (size_t)C * 8, stream);
        int thr = 256;
        fb_err_kernel<<<(max(N, C) + thr - 1) / thr, thr, 0, stream>>>(
            H, W, b, target, ctrs, err_node, arr_idx, (float*)d_out,
            N, C, D, DO, out_size);
        fb_edge_kernel<<<(E + thr - 1) / thr, thr, 0, stream>>>(
            eidx, arr_idx, ctrs, err_node, binsg, E, C);
        fb_finalize_kernel<<<(C + thr - 1) / thr, thr, 0, stream>>>(
            binsg, (float*)d_out, C);
    }
}

// Round 15
// 34.242 us; speedup vs baseline: 3.7327x; 1.0184x over previous
//
#include <hip/hip_runtime.h>

// SpatialMTP1Hop (R15): zero-DS-pipe err_node.
// R13/R14: occupancy pushes exhausted (err+bkt sum, never overlap; 2-4x waves
// = no change). err (~12.5us vs 8.5 BW floor) still carries 15 shuffle ops/KB
// (ds_bpermute class) in every benched variant. R15 err: ONE ROW PER THREAD,
// 32 float4 loads in 4 pipelined groups of 8, W via compile-time scalar loads
// (s_load pipe), zero shuffles/LDS/barriers. L2 transactions unchanged vs
// coalesced (L1 absorbs same-line hits). Also: bkt caches src chunk in LDS
// for pass 2 (-6.4MB L2 re-read); final dispatch folded into reduce (atomic
// out[0], proven absmax-0 R2-R9).

#define CNT_SHIFT 44
#define ERR_SCALE 67108864.0f     // 2^26 fixed-point for err
#define BKT_SHIFT 8
#define BKT_SIZE  256
#define P2B       256             // bucketize blocks
#define BKT_THR   1024
#define STASH     6272            // u32 per block region (>= max chunk 6252)
#define PREF_STRIDE 200           // u16 slots per source block (NB+1 <= 200)

__device__ __forceinline__ int owner_fn(int s, bool fast, int C,
                                        const int* __restrict__ arr_idx,
                                        const int* __restrict__ centers) {
    if (fast) return (s < C) ? s : -1;
    int i = arr_idx[s];
    return ((unsigned)i < (unsigned)C && centers[i] == s) ? i : -1;
}

// D1: prep (blocks < NBV) + err_node (one row per thread, zero DS ops).
__global__ __launch_bounds__(256)
void prep_err_kernel(const float* __restrict__ H, const float* __restrict__ W,
                     const float* __restrict__ b, const float* __restrict__ target,
                     const int* __restrict__ centers,
                     float* __restrict__ err_node,
                     int* __restrict__ arr_idx,
                     int* __restrict__ flagpart,
                     float* __restrict__ out,
                     int N, int C, int NBV, int out_size) {
    __shared__ int ok;
    const int t = threadIdx.x;
    const int gtid = blockIdx.x * 256 + t;

    // ---- prep role (blocks < NBV only; contains the only barriers) ----
    if (blockIdx.x < NBV) {
        if (t == 0) ok = 1;
        __syncthreads();
        bool mism = false;
        if (gtid < C) {
            int c = centers[gtid];
            arr_idx[c] = gtid;             // scatter-only, no sentinel needed
            mism = (c != gtid);
        }
        if (__ballot(mism) != 0ull && (t & 63) == 0) atomicAnd(&ok, 0);
        __syncthreads();
        if (t == 0) flagpart[blockIdx.x] = ok;
    }
    if (gtid < out_size) out[gtid] = 0.f;

    // ---- err role: node = gtid; full row in 4 pipelined groups of 8 float4 ----
    const int node = gtid;
    if (node >= N) return;
    const float4* Hr = reinterpret_cast<const float4*>(H) + (size_t)node * 32;

    float a0 = 0.f, a1 = 0.f, a2 = 0.f;
    float4 ra[8], rb[8];

    #define LOADG(arr, g)                                                   \
        { _Pragma("unroll")                                                 \
          for (int i = 0; i < 8; ++i) arr[i] = Hr[(g) * 8 + i]; }
    // W offsets are compile-time -> scalar loads (s_load pipe)
    #define COMPG(arr, g)                                                   \
        { _Pragma("unroll")                                                 \
          for (int i = 0; i < 8; ++i) {                                     \
              float hx[4] = {arr[i].x, arr[i].y, arr[i].z, arr[i].w};       \
              _Pragma("unroll")                                             \
              for (int e = 0; e < 4; ++e) {                                 \
                  const int k = (g) * 32 + i * 4 + e;                       \
                  a0 += hx[e] * W[k * 3 + 0];                               \
                  a1 += hx[e] * W[k * 3 + 1];                               \
                  a2 += hx[e] * W[k * 3 + 2];                               \
              }                                                             \
          } }

    LOADG(ra, 0) LOADG(rb, 1)
    COMPG(ra, 0) LOADG(ra, 2)
    COMPG(rb, 1) LOADG(rb, 3)
    COMPG(ra, 2) COMPG(rb, 3)
    #undef LOADG
    #undef COMPG

    float e0 = a0 + b[0] - target[(size_t)node * 3 + 0];
    float e1 = a1 + b[1] - target[(size_t)node * 3 + 1];
    float e2 = a2 + b[2] - target[(size_t)node * 3 + 2];
    err_node[node] = (e0 * e0 + e1 * e1 + e2 * e2) * (1.0f / 3.0f);
}

// D2: bucketize (block-local counting sort), 1024 thr, src cached in LDS.
__global__ __launch_bounds__(BKT_THR)
void bucketize_kernel(const int* __restrict__ eidx,
                      const int* __restrict__ centers,
                      const int* __restrict__ arr_idx,
                      const int* __restrict__ flagpart,
                      unsigned short* __restrict__ pref_g,
                      unsigned int* __restrict__ pairs,
                      int E, int C, int NB, int NBV) {
    __shared__ unsigned int stash[STASH];
    __shared__ int          src_c[STASH];
    __shared__ unsigned int hist[256];
    __shared__ unsigned int scan[256];
    __shared__ unsigned int total_sh;
    __shared__ int okf;
    const int t = threadIdx.x;

    if (t == 0) okf = 1;
    if (t < 256) hist[t] = 0u;
    __syncthreads();
    bool my_ok = (t < NBV) ? (flagpart[t] != 0) : true;
    if (__ballot(!my_ok) != 0ull && (t & 63) == 0) atomicAnd(&okf, 0);
    __syncthreads();
    const bool fast = (okf != 0);

    const int E4     = E >> 2;                    // (E&3)==0 host-gated
    const int chunk4 = (E4 + P2B - 1) / P2B;
    const int c0     = blockIdx.x * chunk4;
    const int c1     = min(E4, c0 + chunk4);
    const int4* r0 = reinterpret_cast<const int4*>(eidx);
    const int4* r1 = reinterpret_cast<const int4*>(eidx + E);

    // pass 1: histogram + cache src in LDS
    for (int i = c0 + t; i < c1; i += BKT_THR) {
        int4 s4 = r0[i];
        reinterpret_cast<int4*>(src_c)[i - c0] = s4;
        int ss[4] = {s4.x, s4.y, s4.z, s4.w};
        #pragma unroll
        for (int k = 0; k < 4; ++k) {
            int o = owner_fn(ss[k], fast, C, arr_idx, centers);
            if (o >= 0) atomicAdd(&hist[(unsigned)o >> BKT_SHIFT], 1u);
        }
    }
    __syncthreads();
    if (t < 256) scan[t] = hist[t];
    __syncthreads();
    for (int off = 1; off < 256; off <<= 1) {
        unsigned v = (t < 256 && t >= off) ? scan[t - off] : 0u;
        __syncthreads();
        if (t < 256 && t >= off) scan[t] += v;
        __syncthreads();
    }
    if (t < 256) {
        unsigned pre = (t == 0) ? 0u : scan[t - 1];
        hist[t] = pre;                               // cursor
        if (t <= NB)
            pref_g[(size_t)blockIdx.x * PREF_STRIDE + t] = (unsigned short)pre;
    }
    if (t == 0) total_sh = scan[255];
    __syncthreads();
    // pass 2: LDS scatter (src from LDS, dst from global)
    for (int i = c0 + t; i < c1; i += BKT_THR) {
        int4 d4 = r1[i];
        int4 s4 = reinterpret_cast<const int4*>(src_c)[i - c0];
        int ss[4] = {s4.x, s4.y, s4.z, s4.w};
        int dd[4] = {d4.x, d4.y, d4.z, d4.w};
        #pragma unroll
        for (int k = 0; k < 4; ++k) {
            int o = owner_fn(ss[k], fast, C, arr_idx, centers);
            if (o >= 0) {
                unsigned bk = (unsigned)o >> BKT_SHIFT;
                unsigned pos = atomicAdd(&hist[bk], 1u);
                stash[pos] = (((unsigned)o & (BKT_SIZE - 1)) << 17)
                           | (unsigned)dd[k];
            }
        }
    }
    __syncthreads();
    // stream out only the used entries (coalesced uint4)
    {
        unsigned nvec = (total_sh + 3u) >> 2;
        uint4*       dg = reinterpret_cast<uint4*>(pairs + (size_t)blockIdx.x * STASH);
        const uint4* sg = reinterpret_cast<const uint4*>(stash);
        for (unsigned i = t; i < nvec; i += BKT_THR) dg[i] = sg[i];
    }
}

// D3: per-bucket reduce, 1024 threads, 4 threads per source segment;
//     block term atomically added to out[0] (out zeroed in prep).
__global__ __launch_bounds__(1024)
void reduce_kernel(const unsigned int* __restrict__ pairs,
                   const unsigned short* __restrict__ pref_g,
                   const float* __restrict__ err_node,
                   float* __restrict__ out, int C, float invC) {
    __shared__ unsigned long long bins[BKT_SIZE];
    __shared__ float wsum[16];
    const int bk = blockIdx.x, t = threadIdx.x;
    if (t < BKT_SIZE) bins[t] = 0ull;
    __syncthreads();
    {
        const int seg = t >> 2;            // source block 0..255
        const int j   = t & 3;
        const size_t pb = (size_t)seg * PREF_STRIDE;
        unsigned start = pref_g[pb + bk];
        unsigned end   = pref_g[pb + bk + 1];
        const unsigned int* reg = pairs + (size_t)seg * STASH;
        for (unsigned i = start + j; i < end; i += 4) {
            unsigned p = reg[i];
            float err = err_node[p & 0x1FFFFu];
            atomicAdd(&bins[p >> 17],
                      (1ull << CNT_SHIFT) + (unsigned long long)(err * ERR_SCALE));
        }
    }
    __syncthreads();
    float term = 0.f;
    if (t < BKT_SIZE) {
        int center = bk * BKT_SIZE + t;
        if (center < C) {
            unsigned long long u = bins[t];
            float cnt = (float)(u >> CNT_SHIFT);
            float es  = (float)(u & ((1ull << CNT_SHIFT) - 1)) * (1.0f / ERR_SCALE);
            term = es / fmaxf(cnt, 1.0f);
        }
    }
    #pragma unroll
    for (int m = 32; m > 0; m >>= 1) term += __shfl_down(term, m, 64);
    if ((t & 63) == 0) wsum[t >> 6] = term;
    __syncthreads();
    if (t == 0) {
        float s = 0.f;
        #pragma unroll
        for (int w = 0; w < 16; ++w) s += wsum[w];
        atomicAdd(out, s * invC);
    }
}

// ================= fallback (general shapes / small ws) =================
__global__ __launch_bounds__(256)
void fb_err_kernel(const float* __restrict__ H, const float* __restrict__ W,
                   const float* __restrict__ b, const float* __restrict__ target,
                   const int* __restrict__ centers,
                   float* __restrict__ err_node, int* __restrict__ arr_idx,
                   float* __restrict__ out, int N, int C, int D, int DO,
                   int out_size) {
    int gtid = blockIdx.x * blockDim.x + threadIdx.x;
    if (gtid < C) arr_idx[centers[gtid]] = gtid;
    if (gtid < out_size) out[gtid] = 0.f;
    if (gtid < N) {
        float acc = 0.f;
        for (int j = 0; j < DO; ++j) {
            float a = b[j];
            for (int r = 0; r < D; ++r)
                a += H[(size_t)gtid * D + r] * W[(size_t)r * DO + j];
            float e = a - target[(size_t)gtid * DO + j];
            acc += e * e;
        }
        err_node[gtid] = acc / (float)DO;
    }
}

__global__ void fb_edge_kernel(const int* __restrict__ eidx,
                               const int* __restrict__ arr_idx,
                               const int* __restrict__ centers,
                               const float* __restrict__ err_node,
                               unsigned long long* __restrict__ binsg,
                               int E, int C) {
    int e = blockIdx.x * blockDim.x + threadIdx.x;
    if (e >= E) return;
    int s = eidx[e];
    int o = owner_fn(s, false, C, arr_idx, centers);
    if (o >= 0) {
        int d = eidx[E + e];
        unsigned long long add = (1ull << CNT_SHIFT)
                               + (unsigned long long)(err_node[d] * ERR_SCALE);
        atomicAdd(&binsg[o], add);
    }
}

__global__ void fb_finalize_kernel(const unsigned long long* __restrict__ binsg,
                                   float* __restrict__ out, int C) {
    int i = blockIdx.x * blockDim.x + threadIdx.x;
    float term = 0.f;
    if (i < C) {
        unsigned long long u = binsg[i];
        float cnt = (float)(u >> CNT_SHIFT);
        float es  = (float)(u & ((1ull << CNT_SHIFT) - 1)) * (1.0f / ERR_SCALE);
        term = es / fmaxf(cnt, 1.0f);
    }
    #pragma unroll
    for (int m = 32; m > 0; m >>= 1) term += __shfl_down(term, m, 64);
    __shared__ float wsum[4];
    if ((threadIdx.x & 63) == 0) wsum[threadIdx.x >> 6] = term;
    __syncthreads();
    if (threadIdx.x == 0)
        atomicAdd(out, (wsum[0] + wsum[1] + wsum[2] + wsum[3]) / (float)C);
}

extern "C" void kernel_launch(void* const* d_in, const int* in_sizes, int n_in,
                              void* d_out, int out_size, void* d_ws, size_t ws_size,
                              hipStream_t stream) {
    const float* H      = (const float*)d_in[0];
    const float* W      = (const float*)d_in[1];
    const float* b      = (const float*)d_in[2];
    const float* target = (const float*)d_in[3];
    const int*   eidx   = (const int*)d_in[4];
    const int*   ctrs   = (const int*)d_in[5];

    const int DO = in_sizes[2];
    const int D  = in_sizes[1] / DO;     // 128
    const int N  = in_sizes[0] / D;      // 100000
    const int E  = in_sizes[4] / 2;      // 1600000
    const int C  = in_sizes[5];          // 50000
    const int NB  = (C + BKT_SIZE - 1) >> BKT_SHIFT;  // 196
    const int NBV = (C + 255) / 256;                  // 196
    const int EB  = (N + 255) / 256;                  // err blocks = 391

    size_t off = 0;
    auto take = [&](size_t bytes) {
        void* p = (char*)d_ws + off;
        off = (off + bytes + 255) & ~255ull;
        return p;
    };
    float*          err_node = (float*)take((size_t)N * 4);
    int*            arr_idx  = (int*)take((size_t)N * 4);
    int*            flagpart = (int*)take((size_t)NBV * 4);
    unsigned short* pref_g   = (unsigned short*)take((size_t)P2B * PREF_STRIDE * 2);
    unsigned int*   pairs    = (unsigned int*)((char*)d_ws + off);
    size_t need = off + (size_t)P2B * STASH * 4;

    int chunk_edges = 4 * ((E / 4 + P2B - 1) / P2B);
    bool fits = (ws_size >= need) && (NB + 1 <= PREF_STRIDE) && (NBV <= BKT_THR) &&
                (NBV <= EB) && (N < (1 << 17)) && ((E & 3) == 0) &&
                (chunk_edges <= STASH) && (D == 128) && (DO == 3) && (out_size >= 1);
    if (fits) {
        prep_err_kernel<<<EB, 256, 0, stream>>>(H, W, b, target, ctrs,
                                                err_node, arr_idx, flagpart,
                                                (float*)d_out, N, C, NBV,
                                                out_size);
        bucketize_kernel<<<P2B, BKT_THR, 0, stream>>>(eidx, ctrs, arr_idx,
                                                      flagpart, pref_g, pairs,
                                                      E, C, NB, NBV);
        reduce_kernel<<<NB, 1024, 0, stream>>>(pairs, pref_g, err_node,
                                               (float*)d_out, C, 1.0f / (float)C);
    } else {
        unsigned long long* binsg = (unsigned long long*)((char*)d_ws + off);
        hipMemsetAsync(binsg, 0, (size_t)C * 8, stream);
        int thr = 256;
        fb_err_kernel<<<(max(N, C) + thr - 1) / thr, thr, 0, stream>>>(
            H, W, b, target, ctrs, err_node, arr_idx, (float*)d_out,
            N, C, D, DO, out_size);
        fb_edge_kernel<<<(E + thr - 1) / thr, thr, 0, stream>>>(
            eidx, arr_idx, ctrs, err_node, binsg, E, C);
        fb_finalize_kernel<<<(C + thr - 1) / thr, thr, 0, stream>>>(
            binsg, (float*)d_out, C);
    }
}

// Round 16
// 34.134 us; speedup vs baseline: 3.7445x; 1.0032x over previous
//
#include <hip/hip_runtime.h>

// SpatialMTP1Hop (R16): privatized counting-sort bucketize.
// Ledger at R15: err ~12.5us (pinned at ~4.1TB/s L3-stream ceiling across 4
// structurally different bodies), bkt ~10us for 12.8MB (1.3TB/s -- NOT BW),
// reduce ~4.5, prep ~1.5, overhead ~4. bkt's unique feature: ~1.6M LDS
// atomics from 16 waves onto the SAME 196 hot words + 16-barrier scan.
// R16: per-wave private hist/cursors hw[16][256] (only intra-wave collisions
// remain), single-wave shuffle scan (2 barriers). Exact u64 fixed-point.

#define CNT_SHIFT 44
#define ERR_SCALE 67108864.0f     // 2^26 fixed-point for err
#define BKT_SHIFT 8
#define BKT_SIZE  256
#define P2B       256             // bucketize blocks
#define BKT_THR   1024            // 16 waves
#define NWAVE     16
#define STASH     6272            // u32 per block region (>= max chunk 6252)
#define PREF_STRIDE 200           // u16 slots per source block (NB+1 <= 200)

__device__ __forceinline__ int owner_fn(int s, bool fast, int C,
                                        const int* __restrict__ arr_idx,
                                        const int* __restrict__ centers) {
    if (fast) return (s < C) ? s : -1;
    int i = arr_idx[s];
    return ((unsigned)i < (unsigned)C && centers[i] == s) ? i : -1;
}

// D1: prep (blocks < NBV) + err_node (one row per thread, zero DS ops).
__global__ __launch_bounds__(256)
void prep_err_kernel(const float* __restrict__ H, const float* __restrict__ W,
                     const float* __restrict__ b, const float* __restrict__ target,
                     const int* __restrict__ centers,
                     float* __restrict__ err_node,
                     int* __restrict__ arr_idx,
                     int* __restrict__ flagpart,
                     float* __restrict__ out,
                     int N, int C, int NBV, int out_size) {
    __shared__ int ok;
    const int t = threadIdx.x;
    const int gtid = blockIdx.x * 256 + t;

    if (blockIdx.x < NBV) {
        if (t == 0) ok = 1;
        __syncthreads();
        bool mism = false;
        if (gtid < C) {
            int c = centers[gtid];
            arr_idx[c] = gtid;             // scatter-only, no sentinel needed
            mism = (c != gtid);
        }
        if (__ballot(mism) != 0ull && (t & 63) == 0) atomicAnd(&ok, 0);
        __syncthreads();
        if (t == 0) flagpart[blockIdx.x] = ok;
    }
    if (gtid < out_size) out[gtid] = 0.f;

    const int node = gtid;
    if (node >= N) return;
    const float4* Hr = reinterpret_cast<const float4*>(H) + (size_t)node * 32;

    float a0 = 0.f, a1 = 0.f, a2 = 0.f;
    float4 ra[8], rb[8];

    #define LOADG(arr, g)                                                   \
        { _Pragma("unroll")                                                 \
          for (int i = 0; i < 8; ++i) arr[i] = Hr[(g) * 8 + i]; }
    #define COMPG(arr, g)                                                   \
        { _Pragma("unroll")                                                 \
          for (int i = 0; i < 8; ++i) {                                     \
              float hx[4] = {arr[i].x, arr[i].y, arr[i].z, arr[i].w};       \
              _Pragma("unroll")                                             \
              for (int e = 0; e < 4; ++e) {                                 \
                  const int k = (g) * 32 + i * 4 + e;                       \
                  a0 += hx[e] * W[k * 3 + 0];                               \
                  a1 += hx[e] * W[k * 3 + 1];                               \
                  a2 += hx[e] * W[k * 3 + 2];                               \
              }                                                             \
          } }

    LOADG(ra, 0) LOADG(rb, 1)
    COMPG(ra, 0) LOADG(ra, 2)
    COMPG(rb, 1) LOADG(rb, 3)
    COMPG(ra, 2) COMPG(rb, 3)
    #undef LOADG
    #undef COMPG

    float e0 = a0 + b[0] - target[(size_t)node * 3 + 0];
    float e1 = a1 + b[1] - target[(size_t)node * 3 + 1];
    float e2 = a2 + b[2] - target[(size_t)node * 3 + 2];
    err_node[node] = (e0 * e0 + e1 * e1 + e2 * e2) * (1.0f / 3.0f);
}

// D2: bucketize, per-wave privatized hist/cursors, single-wave shuffle scan.
__global__ __launch_bounds__(BKT_THR)
void bucketize_kernel(const int* __restrict__ eidx,
                      const int* __restrict__ centers,
                      const int* __restrict__ arr_idx,
                      const int* __restrict__ flagpart,
                      unsigned short* __restrict__ pref_g,
                      unsigned int* __restrict__ pairs,
                      int E, int C, int NB, int NBV) {
    __shared__ unsigned int stash[STASH];
    __shared__ unsigned int hw[NWAVE * 256];   // per-wave hist -> cursors
    __shared__ unsigned int binv[256];         // bin totals -> exclusive base
    __shared__ unsigned int total_sh;
    __shared__ int okf;
    const int t = threadIdx.x;
    const int w = t >> 6;                      // wave id 0..15

    if (t == 0) okf = 1;
    #pragma unroll
    for (int i = 0; i < (NWAVE * 256) / BKT_THR; ++i)
        hw[t + i * BKT_THR] = 0u;
    __syncthreads();
    bool my_ok = (t < NBV) ? (flagpart[t] != 0) : true;
    if (__ballot(!my_ok) != 0ull && (t & 63) == 0) atomicAnd(&okf, 0);
    __syncthreads();
    const bool fast = (okf != 0);

    const int E4     = E >> 2;                    // (E&3)==0 host-gated
    const int chunk4 = (E4 + P2B - 1) / P2B;
    const int c0     = blockIdx.x * chunk4;
    const int c1     = min(E4, c0 + chunk4);
    const int4* r0 = reinterpret_cast<const int4*>(eidx);
    const int4* r1 = reinterpret_cast<const int4*>(eidx + E);
    unsigned int* myh = hw + w * 256;

    // pass 1: per-wave private histogram (intra-wave collisions only)
    for (int i = c0 + t; i < c1; i += BKT_THR) {
        int4 s4 = r0[i];
        int ss[4] = {s4.x, s4.y, s4.z, s4.w};
        #pragma unroll
        for (int k = 0; k < 4; ++k) {
            int o = owner_fn(ss[k], fast, C, arr_idx, centers);
            if (o >= 0) atomicAdd(&myh[(unsigned)o >> BKT_SHIFT], 1u);
        }
    }
    __syncthreads();
    // combine: per-bin exclusive offsets across waves + bin totals
    if (t < 256) {
        unsigned run = 0;
        #pragma unroll
        for (int ww = 0; ww < NWAVE; ++ww) {
            unsigned v = hw[ww * 256 + t];
            hw[ww * 256 + t] = run;            // exclusive within bin
            run += v;
        }
        binv[t] = run;                         // bin total
    }
    __syncthreads();
    // single-wave exclusive scan of binv[0..255] (4 elems/lane + shfl_up)
    if (t < 64) {
        unsigned v0 = binv[4 * t], v1 = binv[4 * t + 1];
        unsigned v2 = binv[4 * t + 2], v3 = binv[4 * t + 3];
        unsigned s0 = v0, s01 = v0 + v1, s012 = s01 + v2;
        unsigned lt = s012 + v3;
        unsigned sum = lt;
        #pragma unroll
        for (int d = 1; d < 64; d <<= 1) {
            unsigned x = __shfl_up(sum, d, 64);
            if (t >= d) sum += x;
        }
        unsigned excl = sum - lt;
        binv[4 * t]     = excl;                // in-place: reads done above
        binv[4 * t + 1] = excl + s0;
        binv[4 * t + 2] = excl + s01;
        binv[4 * t + 3] = excl + s012;
        if (t == 63) total_sh = sum;
    }
    __syncthreads();
    // bias per-wave cursors by bin base; emit prefix table
    if (t < 256) {
        unsigned bb = binv[t];
        if (t <= NB)
            pref_g[(size_t)blockIdx.x * PREF_STRIDE + t] = (unsigned short)bb;
        #pragma unroll
        for (int ww = 0; ww < NWAVE; ++ww)
            hw[ww * 256 + t] += bb;
    }
    __syncthreads();
    // pass 2: scatter via the wave's OWN cursors
    for (int i = c0 + t; i < c1; i += BKT_THR) {
        int4 s4 = r0[i];
        int4 d4 = r1[i];
        int ss[4] = {s4.x, s4.y, s4.z, s4.w};
        int dd[4] = {d4.x, d4.y, d4.z, d4.w};
        #pragma unroll
        for (int k = 0; k < 4; ++k) {
            int o = owner_fn(ss[k], fast, C, arr_idx, centers);
            if (o >= 0) {
                unsigned bk = (unsigned)o >> BKT_SHIFT;
                unsigned pos = atomicAdd(&myh[bk], 1u);
                stash[pos] = (((unsigned)o & (BKT_SIZE - 1)) << 17)
                           | (unsigned)dd[k];
            }
        }
    }
    __syncthreads();
    // stream out only the used entries (coalesced uint4)
    {
        unsigned nvec = (total_sh + 3u) >> 2;
        uint4*       dg = reinterpret_cast<uint4*>(pairs + (size_t)blockIdx.x * STASH);
        const uint4* sg = reinterpret_cast<const uint4*>(stash);
        for (unsigned i = t; i < nvec; i += BKT_THR) dg[i] = sg[i];
    }
}

// D3: per-bucket reduce, 1024 threads, 4 threads per source segment;
//     block term atomically added to out[0] (out zeroed in prep).
__global__ __launch_bounds__(1024)
void reduce_kernel(const unsigned int* __restrict__ pairs,
                   const unsigned short* __restrict__ pref_g,
                   const float* __restrict__ err_node,
                   float* __restrict__ out, int C, float invC) {
    __shared__ unsigned long long bins[BKT_SIZE];
    __shared__ float wsum[16];
    const int bk = blockIdx.x, t = threadIdx.x;
    if (t < BKT_SIZE) bins[t] = 0ull;
    __syncthreads();
    {
        const int seg = t >> 2;            // source block 0..255
        const int j   = t & 3;
        const size_t pb = (size_t)seg * PREF_STRIDE;
        unsigned start = pref_g[pb + bk];
        unsigned end   = pref_g[pb + bk + 1];
        const unsigned int* reg = pairs + (size_t)seg * STASH;
        for (unsigned i = start + j; i < end; i += 4) {
            unsigned p = reg[i];
            float err = err_node[p & 0x1FFFFu];
            atomicAdd(&bins[p >> 17],
                      (1ull << CNT_SHIFT) + (unsigned long long)(err * ERR_SCALE));
        }
    }
    __syncthreads();
    float term = 0.f;
    if (t < BKT_SIZE) {
        int center = bk * BKT_SIZE + t;
        if (center < C) {
            unsigned long long u = bins[t];
            float cnt = (float)(u >> CNT_SHIFT);
            float es  = (float)(u & ((1ull << CNT_SHIFT) - 1)) * (1.0f / ERR_SCALE);
            term = es / fmaxf(cnt, 1.0f);
        }
    }
    #pragma unroll
    for (int m = 32; m > 0; m >>= 1) term += __shfl_down(term, m, 64);
    if ((t & 63) == 0) wsum[t >> 6] = term;
    __syncthreads();
    if (t == 0) {
        float s = 0.f;
        #pragma unroll
        for (int w = 0; w < 16; ++w) s += wsum[w];
        atomicAdd(out, s * invC);
    }
}

// ================= fallback (general shapes / small ws) =================
__global__ __launch_bounds__(256)
void fb_err_kernel(const float* __restrict__ H, const float* __restrict__ W,
                   const float* __restrict__ b, const float* __restrict__ target,
                   const int* __restrict__ centers,
                   float* __restrict__ err_node, int* __restrict__ arr_idx,
                   float* __restrict__ out, int N, int C, int D, int DO,
                   int out_size) {
    int gtid = blockIdx.x * blockDim.x + threadIdx.x;
    if (gtid < C) arr_idx[centers[gtid]] = gtid;
    if (gtid < out_size) out[gtid] = 0.f;
    if (gtid < N) {
        float acc = 0.f;
        for (int j = 0; j < DO; ++j) {
            float a = b[j];
            for (int r = 0; r < D; ++r)
                a += H[(size_t)gtid * D + r] * W[(size_t)r * DO + j];
            float e = a - target[(size_t)gtid * DO + j];
            acc += e * e;
        }
        err_node[gtid] = acc / (float)DO;
    }
}

__global__ void fb_edge_kernel(const int* __restrict__ eidx,
                               const int* __restrict__ arr_idx,
                               const int* __restrict__ centers,
                               const float* __restrict__ err_node,
                               unsigned long long* __restrict__ binsg,
                               int E, int C) {
    int e = blockIdx.x * blockDim.x + threadIdx.x;
    if (e >= E) return;
    int s = eidx[e];
    int o = owner_fn(s, false, C, arr_idx, centers);
    if (o >= 0) {
        int d = eidx[E + e];
        unsigned long long add = (1ull << CNT_SHIFT)
                               + (unsigned long long)(err_node[d] * ERR_SCALE);
        atomicAdd(&binsg[o], add);
    }
}

__global__ void fb_finalize_kernel(const unsigned long long* __restrict__ binsg,
                                   float* __restrict__ out, int C) {
    int i = blockIdx.x * blockDim.x + threadIdx.x;
    float term = 0.f;
    if (i < C) {
        unsigned long long u = binsg[i];
        float cnt = (float)(u >> CNT_SHIFT);
        float es  = (float)(u & ((1ull << CNT_SHIFT) - 1)) * (1.0f / ERR_SCALE);
        term = es / fmaxf(cnt, 1.0f);
    }
    #pragma unroll
    for (int m = 32; m > 0; m >>= 1) term += __shfl_down(term, m, 64);
    __shared__ float wsum[4];
    if ((threadIdx.x & 63) == 0) wsum[threadIdx.x >> 6] = term;
    __syncthreads();
    if (threadIdx.x == 0)
        atomicAdd(out, (wsum[0] + wsum[1] + wsum[2] + wsum[3]) / (float)C);
}

extern "C" void kernel_launch(void* const* d_in, const int* in_sizes, int n_in,
                              void* d_out, int out_size, void* d_ws, size_t ws_size,
                              hipStream_t stream) {
    const float* H      = (const float*)d_in[0];
    const float* W      = (const float*)d_in[1];
    const float* b      = (const float*)d_in[2];
    const float* target = (const float*)d_in[3];
    const int*   eidx   = (const int*)d_in[4];
    const int*   ctrs   = (const int*)d_in[5];

    const int DO = in_sizes[2];
    const int D  = in_sizes[1] / DO;     // 128
    const int N  = in_sizes[0] / D;      // 100000
    const int E  = in_sizes[4] / 2;      // 1600000
    const int C  = in_sizes[5];          // 50000
    const int NB  = (C + BKT_SIZE - 1) >> BKT_SHIFT;  // 196
    const int NBV = (C + 255) / 256;                  // 196
    const int EB  = (N + 255) / 256;                  // err blocks = 391

    size_t off = 0;
    auto take = [&](size_t bytes) {
        void* p = (char*)d_ws + off;
        off = (off + bytes + 255) & ~255ull;
        return p;
    };
    float*          err_node = (float*)take((size_t)N * 4);
    int*            arr_idx  = (int*)take((size_t)N * 4);
    int*            flagpart = (int*)take((size_t)NBV * 4);
    unsigned short* pref_g   = (unsigned short*)take((size_t)P2B * PREF_STRIDE * 2);
    unsigned int*   pairs    = (unsigned int*)((char*)d_ws + off);
    size_t need = off + (size_t)P2B * STASH * 4;

    int chunk_edges = 4 * ((E / 4 + P2B - 1) / P2B);
    bool fits = (ws_size >= need) && (NB + 1 <= PREF_STRIDE) && (NBV <= BKT_THR) &&
                (NBV <= EB) && (N < (1 << 17)) && ((E & 3) == 0) &&
                (chunk_edges <= STASH) && (D == 128) && (DO == 3) && (out_size >= 1);
    if (fits) {
        prep_err_kernel<<<EB, 256, 0, stream>>>(H, W, b, target, ctrs,
                                                err_node, arr_idx, flagpart,
                                                (float*)d_out, N, C, NBV,
                                                out_size);
        bucketize_kernel<<<P2B, BKT_THR, 0, stream>>>(eidx, ctrs, arr_idx,
                                                      flagpart, pref_g, pairs,
                                                      E, C, NB, NBV);
        reduce_kernel<<<NB, 1024, 0, stream>>>(pairs, pref_g, err_node,
                                               (float*)d_out, C, 1.0f / (float)C);
    } else {
        unsigned long long* binsg = (unsigned long long*)((char*)d_ws + off);
        hipMemsetAsync(binsg, 0, (size_t)C * 8, stream);
        int thr = 256;
        fb_err_kernel<<<(max(N, C) + thr - 1) / thr, thr, 0, stream>>>(
            H, W, b, target, ctrs, err_node, arr_idx, (float*)d_out,
            N, C, D, DO, out_size);
        fb_edge_kernel<<<(E + thr - 1) / thr, thr, 0, stream>>>(
            eidx, arr_idx, ctrs, err_node, binsg, E, C);
        fb_finalize_kernel<<<(C + thr - 1) / thr, thr, 0, stream>>>(
            binsg, (float*)d_out, C);
    }
}